// Round 1
// baseline (659.243 us; speedup 1.0000x reference)
//
#include <hip/hip_runtime.h>
#include <hip/hip_bf16.h>

#define TT 336
#define NF 321
#define NB 64
#define NSER (NB * NF)   // 20544 series

// ---------------------------------------------------------------------------
// Kernel 1: transpose [B, T, F] -> [B*F, T] for both arrays (coalesced series)
// ---------------------------------------------------------------------------
__global__ void transpose_k(const float* __restrict__ fc, const float* __restrict__ tg,
                            float* __restrict__ fcT, float* __restrict__ tgT) {
    __shared__ float ta[32][33];
    __shared__ float tb[32][33];
    const int b = blockIdx.z;
    const int t0 = blockIdx.x * 32, f0 = blockIdx.y * 32;
    const int tx = threadIdx.x, ty = threadIdx.y;   // block (32, 8)
    const size_t base = (size_t)b * TT * NF;
#pragma unroll
    for (int k = 0; k < 4; k++) {
        int t = t0 + ty + 8 * k, f = f0 + tx;
        if (t < TT && f < NF) {
            ta[ty + 8 * k][tx] = fc[base + (size_t)t * NF + f];
            tb[ty + 8 * k][tx] = tg[base + (size_t)t * NF + f];
        }
    }
    __syncthreads();
#pragma unroll
    for (int k = 0; k < 4; k++) {
        int f = f0 + ty + 8 * k, t = t0 + tx;
        if (t < TT && f < NF) {
            size_t o = ((size_t)b * NF + f) * TT + t;
            fcT[o] = ta[tx][ty + 8 * k];
            tgT[o] = tb[tx][ty + 8 * k];
        }
    }
}

// ---------------------------------------------------------------------------
// Kernel 2: MSE sum of squared diffs, fp64 accumulate
// ---------------------------------------------------------------------------
__global__ void mse_k(const float* __restrict__ fc, const float* __restrict__ tg,
                      double* __restrict__ acc) {
    const size_t N4 = (size_t)NB * TT * NF / 4;
    const float4* a4 = (const float4*)fc;
    const float4* b4 = (const float4*)tg;
    double s = 0.0;
    for (size_t i = (size_t)blockIdx.x * blockDim.x + threadIdx.x; i < N4;
         i += (size_t)gridDim.x * blockDim.x) {
        float4 a = a4[i], b = b4[i];
        double d0 = (double)a.x - (double)b.x;
        double d1 = (double)a.y - (double)b.y;
        double d2 = (double)a.z - (double)b.z;
        double d3 = (double)a.w - (double)b.w;
        s += d0 * d0 + d1 * d1 + d2 * d2 + d3 * d3;
    }
    for (int off = 32; off; off >>= 1) s += __shfl_down(s, off, 64);
    __shared__ double wsum[4];
    int flat = threadIdx.x;
    int lane = flat & 63, wid = flat >> 6;
    if (lane == 0) wsum[wid] = s;
    __syncthreads();
    if (flat == 0) {
        double tot = wsum[0] + wsum[1] + wsum[2] + wsum[3];
        atomicAdd(&acc[0], tot);
    }
}

// ---------------------------------------------------------------------------
// Kernel 3: per-series structural loss. One 64-lane wave per series.
// acc[1] += sum of patch losses, acc[2] += patch count  (fp64 atomics)
// ---------------------------------------------------------------------------
__global__ __launch_bounds__(64) void series_k(const float* __restrict__ fcG,
                                               const float* __restrict__ tgG,
                                               int transposed,
                                               double* __restrict__ acc) {
    const int n = blockIdx.x;
    const int lane = threadIdx.x;
    __shared__ float stg[TT];
    __shared__ float sfc[TT];
    __shared__ float4 zbuf[84];
    __shared__ double cs[5][TT + 1];

    // ---- load series into LDS ----
    if (transposed) {
        const float* tp = tgG + (size_t)n * TT;
        const float* fp = fcG + (size_t)n * TT;
        for (int t = lane; t < TT; t += 64) { stg[t] = tp[t]; sfc[t] = fp[t]; }
    } else {
        int b = n / NF, f = n - b * NF;
        const float* tp = tgG + (size_t)b * TT * NF + f;
        const float* fp = fcG + (size_t)b * TT * NF + f;
        for (int t = lane; t < TT; t += 64) {
            stg[t] = tp[(size_t)t * NF];
            sfc[t] = fp[(size_t)t * NF];
        }
    }
    __syncthreads();

    // ---- radix-4 fold: W_336^84 = -i.  z_f[t] depends only on f mod 4 ----
    for (int t = lane; t < 84; t += 64) {
        float x0 = stg[t], x1 = stg[t + 84], x2 = stg[t + 168], x3 = stg[t + 252];
        float a = x0 + x2, b2 = x1 + x3, c = x0 - x2, d = x1 - x3;
        float4 v; v.x = a + b2; v.y = a - b2; v.z = c; v.w = d;
        zbuf[t] = v;
    }
    __syncthreads();

    // ---- DFT magnitudes, bins f = 1..168, 3 bins per lane (fused loop) ----
    const double TWOPI = 6.283185307179586476925286766559;
    int fb[3] = {1 + lane, 65 + lane, 129 + lane};
    float cc[3], sn[3], re[3], im[3], cd[3], sd[3], sgn[3];
    int selA[3];
#pragma unroll
    for (int q = 0; q < 3; q++) {
        int f = fb[q], cls = f & 3;
        double dl = (double)f * (TWOPI / 336.0);
        cd[q] = (float)cos(dl);
        sd[q] = (float)sin(dl);
        cc[q] = 1.0f; sn[q] = 0.0f; re[q] = 0.0f; im[q] = 0.0f;
        sgn[q] = (cls == 1) ? -1.0f : ((cls == 3) ? 1.0f : 0.0f);
        selA[q] = (cls == 0) ? 0 : ((cls == 2) ? 1 : 2);
    }
    for (int t = 0; t < 84; t++) {
        float4 zv = zbuf[t];
#pragma unroll
        for (int q = 0; q < 3; q++) {
            float zr = (selA[q] == 0) ? zv.x : ((selA[q] == 1) ? zv.y : zv.z);
            float zi = sgn[q] * zv.w;
            re[q] = fmaf(zr, cc[q], re[q]);
            re[q] = fmaf(zi, sn[q], re[q]);
            im[q] = fmaf(zi, cc[q], im[q]);
            im[q] = fmaf(-zr, sn[q], im[q]);
            float nc = fmaf(cc[q], cd[q], -(sn[q] * sd[q]));
            float ns = fmaf(sn[q], cd[q], cc[q] * sd[q]);
            cc[q] = nc; sn[q] = ns;
        }
    }

    // ---- top-3 by amplitude (ties -> lower freq), 64-bit keys ----
    unsigned long long k0 = 0, k1 = 0, k2 = 0;
    auto INS = [&](unsigned long long x) {
        unsigned long long hi = (k0 > x) ? k0 : x;
        unsigned long long lo = (k0 > x) ? x : k0;
        k0 = hi;
        unsigned long long hi1 = (k1 > lo) ? k1 : lo;
        unsigned long long lo1 = (k1 > lo) ? lo : k1;
        k1 = hi1;
        k2 = (k2 > lo1) ? k2 : lo1;
    };
#pragma unroll
    for (int q = 0; q < 3; q++) {
        float a2 = fmaf(re[q], re[q], im[q] * im[q]);
        unsigned long long key =
            ((unsigned long long)__float_as_uint(a2) << 32) |
            (unsigned long long)(0xFFFFFFFFu - (unsigned)fb[q]);
        if (fb[q] > 168) key = 0ull;
        INS(key);
    }
    for (int m = 1; m < 64; m <<= 1) {
        unsigned long long b0 = __shfl_xor(k0, m, 64);
        unsigned long long b1 = __shfl_xor(k1, m, 64);
        unsigned long long b2 = __shfl_xor(k2, m, 64);
        INS(b0); INS(b1); INS(b2);
    }

    // ---- periods, validity, segment counts (wave-uniform) ----
    int fr0 = (int)(0xFFFFFFFFu - (unsigned)(k0 & 0xFFFFFFFFull));
    int fr1 = (int)(0xFFFFFFFFu - (unsigned)(k1 & 0xFFFFFFFFull));
    int fr2 = (int)(0xFFFFFFFFu - (unsigned)(k2 & 0xFFFFFFFFull));
    int P[3] = {TT / fr0, TT / fr1, TT / fr2};
    bool vp[3];
    vp[0] = (P[0] >= 5);
    vp[1] = (P[1] >= 5) && (P[1] != P[0]);
    vp[2] = (P[2] >= 5) && (P[2] != P[0]) && (P[2] != P[1]);
    int nseg[3], rs[3];
    bool hr[3];
#pragma unroll
    for (int q = 0; q < 3; q++) {
        nseg[q] = TT / P[q];
        rs[q] = nseg[q] * P[q];
        hr[q] = vp[q] && ((TT - rs[q]) >= 5);
    }

    // ---- fp64 prefix sums of tg, fc, tg^2, fc^2, tg*fc (337 entries) ----
    double s1 = 0, s2 = 0, s3 = 0, s4 = 0, s5 = 0;
    int t0 = lane * 6;
    if (lane < 56) {
#pragma unroll
        for (int i = 0; i < 6; i++) {
            double a = (double)stg[t0 + i], b = (double)sfc[t0 + i];
            s1 += a; s2 += b; s3 += a * a; s4 += b * b; s5 += a * b;
        }
    }
    double v1 = s1, v2 = s2, v3 = s3, v4 = s4, v5 = s5;
    for (int off = 1; off < 64; off <<= 1) {
        double y1 = __shfl_up(v1, off, 64);
        double y2 = __shfl_up(v2, off, 64);
        double y3 = __shfl_up(v3, off, 64);
        double y4 = __shfl_up(v4, off, 64);
        double y5 = __shfl_up(v5, off, 64);
        if (lane >= off) { v1 += y1; v2 += y2; v3 += y3; v4 += y4; v5 += y5; }
    }
    double e1 = v1 - s1, e2 = v2 - s2, e3 = v3 - s3, e4 = v4 - s4, e5 = v5 - s5;
    if (lane == 0) { cs[0][0] = 0; cs[1][0] = 0; cs[2][0] = 0; cs[3][0] = 0; cs[4][0] = 0; }
    if (lane < 56) {
        double r1 = e1, r2 = e2, r3 = e3, r4 = e4, r5 = e5;
#pragma unroll
        for (int i = 0; i < 6; i++) {
            double a = (double)stg[t0 + i], b = (double)sfc[t0 + i];
            r1 += a; r2 += b; r3 += a * a; r4 += b * b; r5 += a * b;
            cs[0][t0 + i + 1] = r1;
            cs[1][t0 + i + 1] = r2;
            cs[2][t0 + i + 1] = r3;
            cs[3][t0 + i + 1] = r4;
            cs[4][t0 + i + 1] = r5;
        }
    }
    __syncthreads();

    // ---- enumerate candidate patches (3 periods x 68 slots), dedup ----
    int sA[4], eA[4];
    bool kA[4];
    int keptTot = 0;
#pragma unroll
    for (int rI = 0; rI < 4; rI++) {
        int i = lane + 64 * rI;
        bool kept = false;
        int s = 0, e = 0;
        if (i < 204) {
            int k = i / 68, si = i - k * 68;
            if (vp[k]) {
                if (si < nseg[k]) { s = P[k] * si; e = s + P[k]; kept = true; }
                else if (si == nseg[k] && hr[k]) { s = rs[k]; e = TT; kept = true; }
                if (kept) {
#pragma unroll
                    for (int j = 0; j < 2; j++) {
                        if (j < k && vp[j]) {
                            bool dup = (s == rs[j]) && (e == TT) && hr[j];
                            int len = e - s;
                            if (len == P[j] && (s % P[j]) == 0 && (s / P[j]) < nseg[j]) dup = true;
                            if (dup) kept = false;
                        }
                    }
                }
            }
        }
        sA[rI] = s; eA[rI] = e; kA[rI] = kept;
        keptTot += (int)__popcll(__ballot(kept));
    }
    if (keptTot == 0 && lane == 0) { sA[0] = 0; eA[0] = TT; kA[0] = true; }

    // ---- per-patch stats + loss (fp64, mirrors reference formulas) ----
    double lsum = 0.0, lcnt = 0.0;
#pragma unroll
    for (int rI = 0; rI < 4; rI++) {
        if (kA[rI]) {
            int s = sA[rI], e = eA[rI];
            double nn = (double)(e - s);
            double St = cs[0][e] - cs[0][s];
            double Sf = cs[1][e] - cs[1][s];
            double Stt = cs[2][e] - cs[2][s];
            double Sff = cs[3][e] - cs[3][s];
            double Stf = cs[4][e] - cs[4][s];
            double mt = St / nn, mf = Sf / nn;
            double tvs = Stt - nn * mt * mt; tvs = tvs > 0.0 ? tvs : 0.0;
            double fvs = Sff - nn * mf * mf; fvs = fvs > 0.0 ? fvs : 0.0;
            double num = Stf - nn * mt * mf;
            double corr = num / (sqrt(tvs * fvs) + 1e-8);
            double closs = 1.0 - fabs(corr);
            double tvar = tvs / (nn - 1.0), fvar = fvs / (nn - 1.0);
            double vloss = fabs(tvar - fvar) / (tvar + 1e-8);
            double mloss = fabs(mt - mf) / (fabs(mt) + 1e-8);
            lsum += closs + vloss + mloss;
            lcnt += 1.0;
        }
    }
    for (int off = 32; off; off >>= 1) {
        lsum += __shfl_down(lsum, off, 64);
        lcnt += __shfl_down(lcnt, off, 64);
    }
    if (lane == 0) {
        atomicAdd(&acc[1], lsum);
        atomicAdd(&acc[2], lcnt);
    }
}

// ---------------------------------------------------------------------------
// Kernel 4: combine
// ---------------------------------------------------------------------------
__global__ void finalize_k(const double* __restrict__ acc, float* __restrict__ out) {
    double mse = acc[0] / (double)((size_t)NB * TT * NF);
    double avg = (acc[2] > 0.0) ? (acc[1] / acc[2]) : 0.0;
    out[0] = (float)(0.5 * mse + 0.5 * avg);
}

// ---------------------------------------------------------------------------
extern "C" void kernel_launch(void* const* d_in, const int* in_sizes, int n_in,
                              void* d_out, int out_size, void* d_ws, size_t ws_size,
                              hipStream_t stream) {
    const float* fc = (const float*)d_in[0];   // forecast
    const float* tg = (const float*)d_in[1];   // target
    float* out = (float*)d_out;
    char* ws = (char*)d_ws;
    double* acc = (double*)ws;                  // [0]=mse_sum [1]=loss_sum [2]=count

    const size_t offT = 64;
    const size_t bytesT = (size_t)NSER * TT * sizeof(float);
    const bool do_transpose = (ws_size >= offT + 2 * bytesT);
    float* tgT = (float*)(ws + offT);
    float* fcT = (float*)(ws + offT + bytesT);

    hipMemsetAsync(d_ws, 0, 64, stream);

    if (do_transpose) {
        dim3 g((TT + 31) / 32, (NF + 31) / 32, NB);
        dim3 b(32, 8);
        transpose_k<<<g, b, 0, stream>>>(fc, tg, fcT, tgT);
    }
    mse_k<<<1024, 256, 0, stream>>>(fc, tg, acc);

    if (do_transpose) {
        series_k<<<NSER, 64, 0, stream>>>(fcT, tgT, 1, acc);
    } else {
        series_k<<<NSER, 64, 0, stream>>>(fc, tg, 0, acc);
    }
    finalize_k<<<1, 1, 0, stream>>>(acc, out);
}